// Round 8
// baseline (223.137 us; speedup 1.0000x reference)
//
#include <hip/hip_runtime.h>
#include <cstddef>

#define N_IMG 8
#define B_BOX 1000
#define N_CLS 80
#define C1    81
#define K_MAX 100
#define CAND  (N_CLS * K_MAX)   // 8000
#define BPAD  1024              // padded boxes per class row

typedef unsigned long long u64;

// Exact threshold for fl32(a/b) > 0.5 under RNE:  a/b > 0.5 + 2^-25.
// (double)a > (double)b * CMP is exact: 24-bit x 25-bit significands <= 49 bits.
#define CMP_IOU (0.5 + 0x1p-25)

// Skewed index for the u64 sorted-key array: the bitonic j>=256 stages access
// stride-4 u64 (byte stride 32 = bank stride 8) -> 16-way conflict unskewed.
#define SK(p) ((p) + ((p) >> 5))

__device__ __forceinline__ u64 shfl_xor_u64(u64 x, int m) {
    unsigned lo = (unsigned)__shfl_xor((int)(unsigned)(x & 0xffffffffu), m);
    unsigned hi = (unsigned)__shfl_xor((int)(unsigned)(x >> 32), m);
    return ((u64)hi << 32) | lo;
}

__device__ __forceinline__ float4 decode_box(float4 rr, float4 dd) {
    // identical FP sequence to the verified kernels (contraction blocked)
    float w0 = __fadd_rn(__fsub_rn(rr.w, rr.y), 1.0f);
    float h0 = __fadd_rn(__fsub_rn(rr.z, rr.x), 1.0f);
    float x0 = __fadd_rn(rr.y, __fmul_rn(w0, 0.5f));
    float y0 = __fadd_rn(rr.x, __fmul_rn(h0, 0.5f));
    float tx = __fdiv_rn(dd.x, 10.0f);
    float ty = __fdiv_rn(dd.y, 10.0f);
    float tw = __fdiv_rn(dd.z, 5.0f);
    float th = __fdiv_rn(dd.w, 5.0f);
    float cx = __fadd_rn(__fmul_rn(tx, w0), x0);
    float cy = __fadd_rn(__fmul_rn(ty, h0), y0);
    float ww = __fmul_rn(expf(tw), w0);
    float hh = __fmul_rn(expf(th), h0);
    float xx1 = fminf(fmaxf(__fsub_rn(cx, __fmul_rn(0.5f, ww)), 0.0f), 799.0f);
    float yy1 = fminf(fmaxf(__fsub_rn(cy, __fmul_rn(0.5f, hh)), 0.0f), 799.0f);
    float xx2 = fminf(fmaxf(__fadd_rn(cx, __fmul_rn(0.5f, ww)), 0.0f), 799.0f);
    float yy2 = fminf(fmaxf(__fadd_rn(cy, __fmul_rn(0.5f, hh)), 0.0f), 799.0f);
    return make_float4(yy1, xx1, yy2, xx2);
}

// ---------------------------------------------------------------------------
// Decode/transpose (verified round 6, unchanged).
// ---------------------------------------------------------------------------
#define TILE  16
#define NTILE 63
__global__ __launch_bounds__(256) void decode_kernel(
    const float* __restrict__ rois,
    const float* __restrict__ conf,
    const float* __restrict__ deltas,
    float* __restrict__ scoreT,          // [N][80][1024]
    float* __restrict__ boxT,            // [N][80][1024][4]
    float* __restrict__ outRois)
{
    __shared__ float4 lrois[TILE];
    __shared__ float4 lbox[16][TILE + 1];
    __shared__ float  lsc[16][TILE + 1];

    const int tid  = threadIdx.x;
    const int n    = blockIdx.x / NTILE;
    const int tile = blockIdx.x % NTILE;
    const int b0   = tile * TILE;
    const float4 INERT = make_float4(1.0e9f, 1.0e9f, -1.0e9f, -1.0e9f);

    {
        int gidx = blockIdx.x * 256 + tid;
        if (gidx < N_IMG * B_BOX * 4) outRois[gidx] = rois[gidx];
    }

    if (tid < TILE) {
        int b = b0 + tid;
        lrois[tid] = (b < B_BOX) ? ((const float4*)rois)[n * B_BOX + b]
                                 : make_float4(0.f, 0.f, 0.f, 0.f);
    }
    __syncthreads();

    #pragma unroll
    for (int c0 = 0; c0 < N_CLS; c0 += 16) {
        {
            int bl = tid >> 4, ci = tid & 15;
            int b = b0 + bl, c = c0 + ci;
            float4 bx; float sc;
            if (b < B_BOX) {
                float4 dd = ((const float4*)deltas)[(n * B_BOX + b) * N_CLS + c];
                sc = conf[((size_t)(n * B_BOX + b)) * C1 + c];
                bx = decode_box(lrois[bl], dd);
            } else { bx = INERT; sc = 0.0f; }
            lbox[ci][bl] = bx; lsc[ci][bl] = sc;
        }
        __syncthreads();
        {
            int cc = tid >> 4, bl = tid & 15;
            size_t row = ((size_t)n * N_CLS + c0 + cc) * BPAD + b0 + bl;
            ((float4*)boxT)[row] = lbox[cc][bl];
            scoreT[row] = lsc[cc][bl];
        }
        __syncthreads();
    }

    if (tile == 0) {
        for (int i = tid; i < N_CLS * 16; i += 256) {
            int c = i >> 4, b = 1008 + (i & 15);
            size_t row = ((size_t)n * N_CLS + c) * BPAD + b;
            ((float4*)boxT)[row] = INERT;
            scoreT[row] = 0.0f;
        }
    }
}

// ---------------------------------------------------------------------------
// Sort kernel (R7, unchanged): keys only; skewed LDS bitonic; coalesced
// register->global writeback.
// ---------------------------------------------------------------------------
__global__ __launch_bounds__(256) void sort_kernel(
    const float* __restrict__ scoreT,    // [N*80][1024]
    u64* __restrict__ skeyOut)           // [N*80][1024]
{
    __shared__ u64 skeyS[1024 + 32];     // skewed (SK)

    const int blk = blockIdx.x;          // n*N_CLS + c
    const int T = threadIdx.x;

    u64 e[4];
    const size_t row = (size_t)blk * BPAD;
    #pragma unroll
    for (int t = 0; t < 4; t++) {
        const int p = 4 * T + t;
        float sc = scoreT[row + p];
        unsigned sb = (sc > 0.05f) ? __float_as_uint(sc) : 0u;
        e[t] = ((u64)sb << 32) | (unsigned)(1023 - p);
    }

    // --- bitonic sort, descending (CE(p, p^j); direction = (p&k) region) ---
    #pragma unroll 1
    for (int k = 2; k <= 1024; k <<= 1) {
        #pragma unroll 1
        for (int j = (k >> 1); j >= 1; j >>= 1) {
            if (j >= 256) {
                #pragma unroll
                for (int t = 0; t < 4; t++) skeyS[SK(4 * T + t)] = e[t];
                __syncthreads();
                #pragma unroll
                for (int t = 0; t < 4; t++) {
                    int p = 4 * T + t;
                    u64 o = skeyS[SK(p ^ j)];
                    bool keepMin = (((p & j) == 0) == ((p & k) != 0));
                    u64 mn = (e[t] < o) ? e[t] : o;
                    u64 mx = (e[t] < o) ? o : e[t];
                    e[t] = keepMin ? mn : mx;
                }
                __syncthreads();
            } else if (j >= 4) {
                int jl = j >> 2;                        // lane distance
                bool lower = ((T & jl) == 0);           // == ((p&j)==0)
                bool up    = (((4 * T) & k) != 0);      // k>=8: t bits moot
                bool keepMin = (lower == up);
                #pragma unroll
                for (int t = 0; t < 4; t++) {
                    u64 o = shfl_xor_u64(e[t], jl);
                    u64 mn = (e[t] < o) ? e[t] : o;
                    u64 mx = (e[t] < o) ? o : e[t];
                    e[t] = keepMin ? mn : mx;
                }
            } else if (j == 2) {
                #pragma unroll
                for (int t = 0; t < 2; t++) {           // pairs (0,2),(1,3)
                    int p = 4 * T + t;
                    bool up = ((p & k) != 0);
                    u64 a = e[t], b = e[t + 2];
                    bool sw = up ? (a > b) : (a < b);
                    e[t]     = sw ? b : a;
                    e[t + 2] = sw ? a : b;
                }
            } else {                                    // j == 1: (0,1),(2,3)
                #pragma unroll
                for (int t = 0; t < 4; t += 2) {
                    int p = 4 * T + t;
                    bool up = ((p & k) != 0);
                    u64 a = e[t], b = e[t + 1];
                    bool sw = up ? (a > b) : (a < b);
                    e[t]     = sw ? b : a;
                    e[t + 1] = sw ? a : b;
                }
            }
        }
    }

    #pragma unroll
    for (int t = 0; t < 4; t++) skeyOut[row + 4 * T + t] = e[t];
}

// ---------------------------------------------------------------------------
// Scan kernel (R7, unchanged): one wave per (image, class); R3-verbatim
// greedy scan; boxes gathered from boxT via L2/L3.
// ---------------------------------------------------------------------------
__global__ __launch_bounds__(64) void scan_kernel(
    const u64* __restrict__ skey,        // [N*80][1024] sorted desc
    const float* __restrict__ boxT,      // [N*80][1024][4]
    float* __restrict__ candScore,       // [N][CAND]
    float* __restrict__ candBox)         // [N][CAND][4]
{
    __shared__ float4 keptB[K_MAX];
    __shared__ float  keptA[K_MAX];

    const int blk  = blockIdx.x;         // n*N_CLS + c
    const int lane = threadIdx.x;

    const u64*    myKey  = skey + (size_t)blk * BPAD;
    const float4* myBoxT = (const float4*)boxT + (size_t)blk * BPAD;
    float* myScore = candScore + (size_t)blk * K_MAX;
    float* myBox   = candBox   + (size_t)blk * K_MAX * 4;

    int cnt = 0;
    bool done = false;

    for (int t = 0; t < 16 && !done; t++) {
        const u64    key = myKey[t * 64 + lane];
        const int    b   = 1023 - (int)(unsigned)(key & 0xffffffffu);
        const float4 cb  = myBoxT[b];
        const bool valid = (key >> 32) != 0;
        const float carea = __fmul_rn(__fsub_rn(cb.z, cb.x), __fsub_rn(cb.w, cb.y));

        bool sup = false;
        for (int q = 0; q < cnt; q++) {
            float4 kb = keptB[q];
            float  ka = keptA[q];
            float iy1 = fmaxf(kb.x, cb.x), ix1 = fmaxf(kb.y, cb.y);
            float iy2 = fminf(kb.z, cb.z), ix2 = fminf(kb.w, cb.w);
            float ih  = fmaxf(__fsub_rn(iy2, iy1), 0.0f);
            float iw  = fmaxf(__fsub_rn(ix2, ix1), 0.0f);
            float inter = __fmul_rn(ih, iw);
            float den = fmaxf(__fsub_rn(__fadd_rn(ka, carea), inter), 1e-8f);
            sup = sup || ((double)inter > (double)den * CMP_IOU);
        }

        const u64 vmask = __ballot(valid);
        u64 alive = vmask & __ballot(!sup);

        while (alive != 0) {
            const int j = __ffsll(alive) - 1;
            const float bx = __int_as_float(__builtin_amdgcn_readlane(__float_as_int(cb.x), j));
            const float by = __int_as_float(__builtin_amdgcn_readlane(__float_as_int(cb.y), j));
            const float bz = __int_as_float(__builtin_amdgcn_readlane(__float_as_int(cb.z), j));
            const float bw = __int_as_float(__builtin_amdgcn_readlane(__float_as_int(cb.w), j));
            const float ba = __int_as_float(__builtin_amdgcn_readlane(__float_as_int(carea), j));

            if (lane == j) {
                myScore[cnt] = __uint_as_float((unsigned)(key >> 32));
                ((float4*)myBox)[cnt] = cb;
                keptB[cnt] = cb;
                keptA[cnt] = carea;
            }
            cnt++;
            if (cnt >= K_MAX) { done = true; break; }

            alive &= ~(1ull << j);
            if (alive != 0) {
                float iy1 = fmaxf(bx, cb.x), ix1 = fmaxf(by, cb.y);
                float iy2 = fminf(bz, cb.z), ix2 = fminf(bw, cb.w);
                float ih  = fmaxf(__fsub_rn(iy2, iy1), 0.0f);
                float iw  = fmaxf(__fsub_rn(ix2, ix1), 0.0f);
                float inter = __fmul_rn(ih, iw);
                float den = fmaxf(__fsub_rn(__fadd_rn(ba, carea), inter), 1e-8f);
                bool s2 = (double)inter > (double)den * CMP_IOU;
                alive &= ~__ballot(s2);
            }
        }

        if (vmask != ~0ull) done = true;
    }
    for (int q = cnt + lane; q < K_MAX; q += 64) myScore[q] = -1.0f;
}

// ---------------------------------------------------------------------------
// Fallback fused NMS (R3-verbatim, PRE=false inline-decode path) — used only
// if the workspace is too small for the split pipeline.
// ---------------------------------------------------------------------------
__global__ __launch_bounds__(256) void nms_fused_kernel(
    const float* __restrict__ rois,
    const float* __restrict__ conf,
    const float* __restrict__ deltas,
    float* __restrict__ candScore,
    float* __restrict__ candBox)
{
    __shared__ float4 sbox[1024];
    __shared__ u64    skeyS[1024 + 32];
    __shared__ float4 keptB[K_MAX];
    __shared__ float  keptA[K_MAX];

    const int n = blockIdx.x / N_CLS;
    const int c = blockIdx.x % N_CLS;
    const int T = threadIdx.x;
    const float4 INERT = make_float4(1.0e9f, 1.0e9f, -1.0e9f, -1.0e9f);

    u64 e[4];
    #pragma unroll
    for (int t = 0; t < 4; t++) {
        const int p = 4 * T + t;
        if (p < B_BOX) {
            float4 rr = ((const float4*)rois)[n * B_BOX + p];
            float4 dd = ((const float4*)deltas)[(size_t)(n * B_BOX + p) * N_CLS + c];
            float score = conf[((size_t)(n * B_BOX + p)) * C1 + c];
            float4 q = decode_box(rr, dd);
            sbox[p] = q;
            unsigned sb = (score > 0.05f) ? __float_as_uint(score) : 0u;
            e[t] = ((u64)sb << 32) | (unsigned)(1023 - p);
        } else {
            sbox[p] = INERT;
            e[t] = (u64)(unsigned)(1023 - p);
        }
    }

    #pragma unroll 1
    for (int k = 2; k <= 1024; k <<= 1) {
        #pragma unroll 1
        for (int j = (k >> 1); j >= 1; j >>= 1) {
            if (j >= 256) {
                #pragma unroll
                for (int t = 0; t < 4; t++) skeyS[SK(4 * T + t)] = e[t];
                __syncthreads();
                #pragma unroll
                for (int t = 0; t < 4; t++) {
                    int p = 4 * T + t;
                    u64 o = skeyS[SK(p ^ j)];
                    bool keepMin = (((p & j) == 0) == ((p & k) != 0));
                    u64 mn = (e[t] < o) ? e[t] : o;
                    u64 mx = (e[t] < o) ? o : e[t];
                    e[t] = keepMin ? mn : mx;
                }
                __syncthreads();
            } else if (j >= 4) {
                int jl = j >> 2;
                bool lower = ((T & jl) == 0);
                bool up    = (((4 * T) & k) != 0);
                bool keepMin = (lower == up);
                #pragma unroll
                for (int t = 0; t < 4; t++) {
                    u64 o = shfl_xor_u64(e[t], jl);
                    u64 mn = (e[t] < o) ? e[t] : o;
                    u64 mx = (e[t] < o) ? o : e[t];
                    e[t] = keepMin ? mn : mx;
                }
            } else if (j == 2) {
                #pragma unroll
                for (int t = 0; t < 2; t++) {
                    int p = 4 * T + t;
                    bool up = ((p & k) != 0);
                    u64 a = e[t], b = e[t + 2];
                    bool sw = up ? (a > b) : (a < b);
                    e[t]     = sw ? b : a;
                    e[t + 2] = sw ? a : b;
                }
            } else {
                #pragma unroll
                for (int t = 0; t < 4; t += 2) {
                    int p = 4 * T + t;
                    bool up = ((p & k) != 0);
                    u64 a = e[t], b = e[t + 1];
                    bool sw = up ? (a > b) : (a < b);
                    e[t]     = sw ? b : a;
                    e[t + 1] = sw ? a : b;
                }
            }
        }
    }

    #pragma unroll
    for (int t = 0; t < 4; t++) skeyS[SK(4 * T + t)] = e[t];
    __syncthreads();

    if (T >= 64) return;
    const int lane = T;

    float* myScore = candScore + (size_t)n * CAND + c * K_MAX;
    float* myBox   = candBox   + ((size_t)n * CAND + c * K_MAX) * 4;

    int cnt = 0;
    bool done = false;

    for (int t = 0; t < 16 && !done; t++) {
        const int p = t * 64 + lane;
        const u64    key = skeyS[SK(p)];
        const int    b   = 1023 - (int)(unsigned)(key & 0xffffffffu);
        const float4 cb  = sbox[b];
        const bool valid = (key >> 32) != 0;
        const float carea = __fmul_rn(__fsub_rn(cb.z, cb.x), __fsub_rn(cb.w, cb.y));

        bool sup = false;
        for (int q = 0; q < cnt; q++) {
            float4 kb = keptB[q];
            float  ka = keptA[q];
            float iy1 = fmaxf(kb.x, cb.x), ix1 = fmaxf(kb.y, cb.y);
            float iy2 = fminf(kb.z, cb.z), ix2 = fminf(kb.w, cb.w);
            float ih  = fmaxf(__fsub_rn(iy2, iy1), 0.0f);
            float iw  = fmaxf(__fsub_rn(ix2, ix1), 0.0f);
            float inter = __fmul_rn(ih, iw);
            float den = fmaxf(__fsub_rn(__fadd_rn(ka, carea), inter), 1e-8f);
            sup = sup || ((double)inter > (double)den * CMP_IOU);
        }

        const u64 vmask = __ballot(valid);
        u64 alive = vmask & __ballot(!sup);

        while (alive != 0) {
            const int j = __ffsll(alive) - 1;
            const float bx = __int_as_float(__builtin_amdgcn_readlane(__float_as_int(cb.x), j));
            const float by = __int_as_float(__builtin_amdgcn_readlane(__float_as_int(cb.y), j));
            const float bz = __int_as_float(__builtin_amdgcn_readlane(__float_as_int(cb.z), j));
            const float bw = __int_as_float(__builtin_amdgcn_readlane(__float_as_int(cb.w), j));
            const float ba = __int_as_float(__builtin_amdgcn_readlane(__float_as_int(carea), j));

            if (lane == j) {
                myScore[cnt] = __uint_as_float((unsigned)(key >> 32));
                ((float4*)myBox)[cnt] = cb;
                keptB[cnt] = cb;
                keptA[cnt] = carea;
            }
            cnt++;
            if (cnt >= K_MAX) { done = true; break; }

            alive &= ~(1ull << j);
            if (alive != 0) {
                float iy1 = fmaxf(bx, cb.x), ix1 = fmaxf(by, cb.y);
                float iy2 = fminf(bz, cb.z), ix2 = fminf(bw, cb.w);
                float ih  = fmaxf(__fsub_rn(iy2, iy1), 0.0f);
                float iw  = fmaxf(__fsub_rn(ix2, ix1), 0.0f);
                float inter = __fmul_rn(ih, iw);
                float den = fmaxf(__fsub_rn(__fadd_rn(ba, carea), inter), 1e-8f);
                bool s2 = (double)inter > (double)den * CMP_IOU;
                alive &= ~__ballot(s2);
            }
        }

        if (vmask != ~0ull) done = true;
    }
    for (int q = cnt + lane; q < K_MAX; q += 64) myScore[q] = -1.0f;
}

// ---------------------------------------------------------------------------
// Top-K (R8): 100-step k-way merge of the 80 per-class candidate lists,
// which the scan already wrote in descending order (greedy accept order;
// -1 fills keep each list strictly descending in key).  One wave per image.
// Keys are the SAME u64 total order as the verified radix kernel
// ((U<<13)|(8191-i)) => identical selection, order, tie-breaks, num_dets.
// Keys are globally distinct (position term) => unique argmax each step.
// No atomics, no histograms, no multi-wave barriers — replaces the radix
// kernel that stalled 43 us at 0.16% VALUBusy (LDS same-address atomic
// serialization + barrier ladders with zero TLP).
// ---------------------------------------------------------------------------
__global__ __launch_bounds__(64) void topk_kernel(
    const float* __restrict__ candScore,
    const float* __restrict__ candBox,
    float* __restrict__ out)
{
    __shared__ u64 keys[CAND];           // 64 KB
    __shared__ int selQ[K_MAX];

    const int n    = blockIdx.x;
    const int lane = threadIdx.x;
    const float* S = candScore + (size_t)n * CAND;

    for (int i = lane; i < CAND; i += 64) {
        float s = S[i];
        unsigned U = (s > 0.0f) ? __float_as_uint(s) : 0u;
        keys[i] = (((u64)U) << 13) | (unsigned)(8191 - i);
    }
    __syncthreads();

    // merge state: lane l owns list l; lanes 0-15 also own list 64+l.
    // cur + next prefetch keeps the LDS reload off the reduce critical path.
    int r0 = 0, r1 = 0;
    u64 c0 = keys[lane * K_MAX];
    u64 n0 = keys[lane * K_MAX + 1];
    u64 c1 = 0, n1 = 0;
    if (lane < 16) {
        c1 = keys[(64 + lane) * K_MAX];
        n1 = keys[(64 + lane) * K_MAX + 1];
    }

    for (int step = 0; step < K_MAX; ++step) {
        u64 m = (c0 > c1) ? c0 : c1;
        u64 M = m;
        #pragma unroll
        for (int d = 1; d < 64; d <<= 1) {
            u64 o = shfl_xor_u64(M, d);
            if (o > M) M = o;
        }
        if (m == M) {                    // unique owner (keys distinct)
            if (c0 == M) {
                selQ[step] = lane * K_MAX + r0;
                r0++;
                c0 = n0;
                n0 = (r0 + 1 < K_MAX) ? keys[lane * K_MAX + r0 + 1] : 0ull;
            } else {
                selQ[step] = (64 + lane) * K_MAX + r1;
                r1++;
                c1 = n1;
                n1 = (r1 + 1 < K_MAX) ? keys[(64 + lane) * K_MAX + r1 + 1] : 0ull;
            }
        }
    }
    __syncthreads();

    for (int r = lane; r < K_MAX; r += 64) {
        const int q = selQ[r];
        const unsigned u = (unsigned)(keys[q] >> 13);
        const bool valid = (u != 0);
        float4 bx = make_float4(0.f, 0.f, 0.f, 0.f);
        if (valid) bx = ((const float4*)candBox)[(size_t)n * CAND + q];

        ((float4*)out)[n * K_MAX + r] = bx;
        out[N_IMG * K_MAX * 4 + n * K_MAX + r] = valid ? __uint_as_float(u) : 0.0f;
        out[N_IMG * K_MAX * 5 + n * K_MAX + r] = valid ? (float)(q / K_MAX) : 0.0f;
    }

    int cntv = 0;
    for (int r = lane; r < K_MAX; r += 64)
        cntv += ((unsigned)(keys[selQ[r]] >> 13) != 0u) ? 1 : 0;
    #pragma unroll
    for (int d = 1; d < 64; d <<= 1) cntv += __shfl_xor(cntv, d);
    if (lane == 0) out[N_IMG * K_MAX * 6 + n] = (float)cntv;
}

extern "C" void kernel_launch(void* const* d_in, const int* in_sizes, int n_in,
                              void* d_out, int out_size, void* d_ws, size_t ws_size,
                              hipStream_t stream) {
    const float* rois   = (const float*)d_in[0];   // [8][1000][4]
    const float* conf   = (const float*)d_in[1];   // [8][1000][81]
    const float* deltas = (const float*)d_in[2];   // [8][1000][320]
    float* out = (float*)d_out;                    // 36808 floats
    float* ws  = (float*)d_ws;

    float* candScore = ws;                                      // 64000 f
    float* candBox   = candScore + (size_t)N_IMG * CAND;        // 256000 f
    float* scoreT    = candBox + (size_t)N_IMG * CAND * 4;      // 655360 f
    float* boxT      = scoreT + (size_t)N_IMG * N_CLS * BPAD;   // 2621440 f
    u64*   skeyW     = (u64*)(boxT + (size_t)N_IMG * N_CLS * BPAD * 4);
    const size_t needed = ((size_t)N_IMG * CAND * 5
                         + (size_t)N_IMG * N_CLS * BPAD * 5) * sizeof(float)
                        + (size_t)N_IMG * N_CLS * BPAD * sizeof(u64);

    if (ws_size >= needed) {
        decode_kernel<<<N_IMG * NTILE, 256, 0, stream>>>(
            rois, conf, deltas, scoreT, boxT, out + 4808);
        sort_kernel<<<N_IMG * N_CLS, 256, 0, stream>>>(scoreT, skeyW);
        scan_kernel<<<N_IMG * N_CLS, 64, 0, stream>>>(
            skeyW, boxT, candScore, candBox);
        topk_kernel<<<N_IMG, 64, 0, stream>>>(candScore, candBox, out);
    } else {
        nms_fused_kernel<<<N_IMG * N_CLS, 256, 0, stream>>>(
            rois, conf, deltas, candScore, candBox);
        topk_kernel<<<N_IMG, 64, 0, stream>>>(candScore, candBox, out);
        hipMemcpyAsync(out + 4808, rois,
                       (size_t)N_IMG * B_BOX * 4 * sizeof(float),
                       hipMemcpyDeviceToDevice, stream);
    }
}

// Round 9
// 186.029 us; speedup vs baseline: 1.1995x; 1.1995x over previous
//
#include <hip/hip_runtime.h>
#include <cstddef>

#define N_IMG 8
#define B_BOX 1000
#define N_CLS 80
#define C1    81
#define K_MAX 100
#define CAND  (N_CLS * K_MAX)   // 8000
#define BPAD  1024              // padded boxes per class row

typedef unsigned long long u64;

// Exact threshold for fl32(a/b) > 0.5 under RNE:  a/b > 0.5 + 2^-25.
// (double)a > (double)b * CMP is exact: 24-bit x 25-bit significands <= 49 bits.
#define CMP_IOU (0.5 + 0x1p-25)

// Skewed index for the u64 sorted-key array: the bitonic j>=256 stages access
// stride-4 u64 (byte stride 32 = bank stride 8) -> 16-way conflict unskewed.
#define SK(p) ((p) + ((p) >> 5))

__device__ __forceinline__ u64 shfl_xor_u64(u64 x, int m) {
    unsigned lo = (unsigned)__shfl_xor((int)(unsigned)(x & 0xffffffffu), m);
    unsigned hi = (unsigned)__shfl_xor((int)(unsigned)(x >> 32), m);
    return ((u64)hi << 32) | lo;
}

// The verified 1024-key descending bitonic (R3/R7): keys in e[4], p = 4T+t.
// Independent per-t shuffles pipeline; only 3 stages touch LDS (skewed).
__device__ __forceinline__ void bitonic1024(u64 e[4], u64* skeyS, int T) {
    #pragma unroll 1
    for (int k = 2; k <= 1024; k <<= 1) {
        #pragma unroll 1
        for (int j = (k >> 1); j >= 1; j >>= 1) {
            if (j >= 256) {
                #pragma unroll
                for (int t = 0; t < 4; t++) skeyS[SK(4 * T + t)] = e[t];
                __syncthreads();
                #pragma unroll
                for (int t = 0; t < 4; t++) {
                    int p = 4 * T + t;
                    u64 o = skeyS[SK(p ^ j)];
                    bool keepMin = (((p & j) == 0) == ((p & k) != 0));
                    u64 mn = (e[t] < o) ? e[t] : o;
                    u64 mx = (e[t] < o) ? o : e[t];
                    e[t] = keepMin ? mn : mx;
                }
                __syncthreads();
            } else if (j >= 4) {
                int jl = j >> 2;                        // lane distance
                bool lower = ((T & jl) == 0);           // == ((p&j)==0)
                bool up    = (((4 * T) & k) != 0);      // k>=8: t bits moot
                bool keepMin = (lower == up);
                #pragma unroll
                for (int t = 0; t < 4; t++) {
                    u64 o = shfl_xor_u64(e[t], jl);
                    u64 mn = (e[t] < o) ? e[t] : o;
                    u64 mx = (e[t] < o) ? o : e[t];
                    e[t] = keepMin ? mn : mx;
                }
            } else if (j == 2) {
                #pragma unroll
                for (int t = 0; t < 2; t++) {           // pairs (0,2),(1,3)
                    int p = 4 * T + t;
                    bool up = ((p & k) != 0);
                    u64 a = e[t], b = e[t + 2];
                    bool sw = up ? (a > b) : (a < b);
                    e[t]     = sw ? b : a;
                    e[t + 2] = sw ? a : b;
                }
            } else {                                    // j == 1: (0,1),(2,3)
                #pragma unroll
                for (int t = 0; t < 4; t += 2) {
                    int p = 4 * T + t;
                    bool up = ((p & k) != 0);
                    u64 a = e[t], b = e[t + 1];
                    bool sw = up ? (a > b) : (a < b);
                    e[t]     = sw ? b : a;
                    e[t + 1] = sw ? a : b;
                }
            }
        }
    }
}

__device__ __forceinline__ float4 decode_box(float4 rr, float4 dd) {
    // identical FP sequence to the verified kernels (contraction blocked)
    float w0 = __fadd_rn(__fsub_rn(rr.w, rr.y), 1.0f);
    float h0 = __fadd_rn(__fsub_rn(rr.z, rr.x), 1.0f);
    float x0 = __fadd_rn(rr.y, __fmul_rn(w0, 0.5f));
    float y0 = __fadd_rn(rr.x, __fmul_rn(h0, 0.5f));
    float tx = __fdiv_rn(dd.x, 10.0f);
    float ty = __fdiv_rn(dd.y, 10.0f);
    float tw = __fdiv_rn(dd.z, 5.0f);
    float th = __fdiv_rn(dd.w, 5.0f);
    float cx = __fadd_rn(__fmul_rn(tx, w0), x0);
    float cy = __fadd_rn(__fmul_rn(ty, h0), y0);
    float ww = __fmul_rn(expf(tw), w0);
    float hh = __fmul_rn(expf(th), h0);
    float xx1 = fminf(fmaxf(__fsub_rn(cx, __fmul_rn(0.5f, ww)), 0.0f), 799.0f);
    float yy1 = fminf(fmaxf(__fsub_rn(cy, __fmul_rn(0.5f, hh)), 0.0f), 799.0f);
    float xx2 = fminf(fmaxf(__fadd_rn(cx, __fmul_rn(0.5f, ww)), 0.0f), 799.0f);
    float yy2 = fminf(fmaxf(__fadd_rn(cy, __fmul_rn(0.5f, hh)), 0.0f), 799.0f);
    return make_float4(yy1, xx1, yy2, xx2);
}

// ---------------------------------------------------------------------------
// Decode/transpose (verified round 6, unchanged).
// ---------------------------------------------------------------------------
#define TILE  16
#define NTILE 63
__global__ __launch_bounds__(256) void decode_kernel(
    const float* __restrict__ rois,
    const float* __restrict__ conf,
    const float* __restrict__ deltas,
    float* __restrict__ scoreT,          // [N][80][1024]
    float* __restrict__ boxT,            // [N][80][1024][4]
    float* __restrict__ outRois)
{
    __shared__ float4 lrois[TILE];
    __shared__ float4 lbox[16][TILE + 1];
    __shared__ float  lsc[16][TILE + 1];

    const int tid  = threadIdx.x;
    const int n    = blockIdx.x / NTILE;
    const int tile = blockIdx.x % NTILE;
    const int b0   = tile * TILE;
    const float4 INERT = make_float4(1.0e9f, 1.0e9f, -1.0e9f, -1.0e9f);

    {
        int gidx = blockIdx.x * 256 + tid;
        if (gidx < N_IMG * B_BOX * 4) outRois[gidx] = rois[gidx];
    }

    if (tid < TILE) {
        int b = b0 + tid;
        lrois[tid] = (b < B_BOX) ? ((const float4*)rois)[n * B_BOX + b]
                                 : make_float4(0.f, 0.f, 0.f, 0.f);
    }
    __syncthreads();

    #pragma unroll
    for (int c0 = 0; c0 < N_CLS; c0 += 16) {
        {
            int bl = tid >> 4, ci = tid & 15;
            int b = b0 + bl, c = c0 + ci;
            float4 bx; float sc;
            if (b < B_BOX) {
                float4 dd = ((const float4*)deltas)[(n * B_BOX + b) * N_CLS + c];
                sc = conf[((size_t)(n * B_BOX + b)) * C1 + c];
                bx = decode_box(lrois[bl], dd);
            } else { bx = INERT; sc = 0.0f; }
            lbox[ci][bl] = bx; lsc[ci][bl] = sc;
        }
        __syncthreads();
        {
            int cc = tid >> 4, bl = tid & 15;
            size_t row = ((size_t)n * N_CLS + c0 + cc) * BPAD + b0 + bl;
            ((float4*)boxT)[row] = lbox[cc][bl];
            scoreT[row] = lsc[cc][bl];
        }
        __syncthreads();
    }

    if (tile == 0) {
        for (int i = tid; i < N_CLS * 16; i += 256) {
            int c = i >> 4, b = 1008 + (i & 15);
            size_t row = ((size_t)n * N_CLS + c) * BPAD + b;
            ((float4*)boxT)[row] = INERT;
            scoreT[row] = 0.0f;
        }
    }
}

// ---------------------------------------------------------------------------
// Sort kernel (R7, unchanged): keys only; skewed LDS bitonic; coalesced
// register->global writeback.
// ---------------------------------------------------------------------------
__global__ __launch_bounds__(256) void sort_kernel(
    const float* __restrict__ scoreT,    // [N*80][1024]
    u64* __restrict__ skeyOut)           // [N*80][1024]
{
    __shared__ u64 skeyS[1024 + 32];     // skewed (SK)

    const int blk = blockIdx.x;          // n*N_CLS + c
    const int T = threadIdx.x;

    u64 e[4];
    const size_t row = (size_t)blk * BPAD;
    #pragma unroll
    for (int t = 0; t < 4; t++) {
        const int p = 4 * T + t;
        float sc = scoreT[row + p];
        unsigned sb = (sc > 0.05f) ? __float_as_uint(sc) : 0u;
        e[t] = ((u64)sb << 32) | (unsigned)(1023 - p);
    }

    bitonic1024(e, skeyS, T);

    #pragma unroll
    for (int t = 0; t < 4; t++) skeyOut[row + 4 * T + t] = e[t];
}

// ---------------------------------------------------------------------------
// Scan kernel (R7, unchanged): one wave per (image, class); R3-verbatim
// greedy scan; boxes gathered from boxT via L2/L3.
// ---------------------------------------------------------------------------
__global__ __launch_bounds__(64) void scan_kernel(
    const u64* __restrict__ skey,        // [N*80][1024] sorted desc
    const float* __restrict__ boxT,      // [N*80][1024][4]
    float* __restrict__ candScore,       // [N][CAND]
    float* __restrict__ candBox)         // [N][CAND][4]
{
    __shared__ float4 keptB[K_MAX];
    __shared__ float  keptA[K_MAX];

    const int blk  = blockIdx.x;         // n*N_CLS + c
    const int lane = threadIdx.x;

    const u64*    myKey  = skey + (size_t)blk * BPAD;
    const float4* myBoxT = (const float4*)boxT + (size_t)blk * BPAD;
    float* myScore = candScore + (size_t)blk * K_MAX;
    float* myBox   = candBox   + (size_t)blk * K_MAX * 4;

    int cnt = 0;
    bool done = false;

    for (int t = 0; t < 16 && !done; t++) {
        const u64    key = myKey[t * 64 + lane];
        const int    b   = 1023 - (int)(unsigned)(key & 0xffffffffu);
        const float4 cb  = myBoxT[b];
        const bool valid = (key >> 32) != 0;
        const float carea = __fmul_rn(__fsub_rn(cb.z, cb.x), __fsub_rn(cb.w, cb.y));

        bool sup = false;
        for (int q = 0; q < cnt; q++) {
            float4 kb = keptB[q];
            float  ka = keptA[q];
            float iy1 = fmaxf(kb.x, cb.x), ix1 = fmaxf(kb.y, cb.y);
            float iy2 = fminf(kb.z, cb.z), ix2 = fminf(kb.w, cb.w);
            float ih  = fmaxf(__fsub_rn(iy2, iy1), 0.0f);
            float iw  = fmaxf(__fsub_rn(ix2, ix1), 0.0f);
            float inter = __fmul_rn(ih, iw);
            float den = fmaxf(__fsub_rn(__fadd_rn(ka, carea), inter), 1e-8f);
            sup = sup || ((double)inter > (double)den * CMP_IOU);
        }

        const u64 vmask = __ballot(valid);
        u64 alive = vmask & __ballot(!sup);

        while (alive != 0) {
            const int j = __ffsll(alive) - 1;
            const float bx = __int_as_float(__builtin_amdgcn_readlane(__float_as_int(cb.x), j));
            const float by = __int_as_float(__builtin_amdgcn_readlane(__float_as_int(cb.y), j));
            const float bz = __int_as_float(__builtin_amdgcn_readlane(__float_as_int(cb.z), j));
            const float bw = __int_as_float(__builtin_amdgcn_readlane(__float_as_int(cb.w), j));
            const float ba = __int_as_float(__builtin_amdgcn_readlane(__float_as_int(carea), j));

            if (lane == j) {
                myScore[cnt] = __uint_as_float((unsigned)(key >> 32));
                ((float4*)myBox)[cnt] = cb;
                keptB[cnt] = cb;
                keptA[cnt] = carea;
            }
            cnt++;
            if (cnt >= K_MAX) { done = true; break; }

            alive &= ~(1ull << j);
            if (alive != 0) {
                float iy1 = fmaxf(bx, cb.x), ix1 = fmaxf(by, cb.y);
                float iy2 = fminf(bz, cb.z), ix2 = fminf(bw, cb.w);
                float ih  = fmaxf(__fsub_rn(iy2, iy1), 0.0f);
                float iw  = fmaxf(__fsub_rn(ix2, ix1), 0.0f);
                float inter = __fmul_rn(ih, iw);
                float den = fmaxf(__fsub_rn(__fadd_rn(ba, carea), inter), 1e-8f);
                bool s2 = (double)inter > (double)den * CMP_IOU;
                alive &= ~__ballot(s2);
            }
        }

        if (vmask != ~0ull) done = true;
    }
    for (int q = cnt + lane; q < K_MAX; q += 64) myScore[q] = -1.0f;
}

// ---------------------------------------------------------------------------
// Fallback fused NMS (R3-verbatim) — used only if ws too small for split.
// ---------------------------------------------------------------------------
__global__ __launch_bounds__(256) void nms_fused_kernel(
    const float* __restrict__ rois,
    const float* __restrict__ conf,
    const float* __restrict__ deltas,
    float* __restrict__ candScore,
    float* __restrict__ candBox)
{
    __shared__ float4 sbox[1024];
    __shared__ u64    skeyS[1024 + 32];
    __shared__ float4 keptB[K_MAX];
    __shared__ float  keptA[K_MAX];

    const int n = blockIdx.x / N_CLS;
    const int c = blockIdx.x % N_CLS;
    const int T = threadIdx.x;
    const float4 INERT = make_float4(1.0e9f, 1.0e9f, -1.0e9f, -1.0e9f);

    u64 e[4];
    #pragma unroll
    for (int t = 0; t < 4; t++) {
        const int p = 4 * T + t;
        if (p < B_BOX) {
            float4 rr = ((const float4*)rois)[n * B_BOX + p];
            float4 dd = ((const float4*)deltas)[(size_t)(n * B_BOX + p) * N_CLS + c];
            float score = conf[((size_t)(n * B_BOX + p)) * C1 + c];
            float4 q = decode_box(rr, dd);
            sbox[p] = q;
            unsigned sb = (score > 0.05f) ? __float_as_uint(score) : 0u;
            e[t] = ((u64)sb << 32) | (unsigned)(1023 - p);
        } else {
            sbox[p] = INERT;
            e[t] = (u64)(unsigned)(1023 - p);
        }
    }

    bitonic1024(e, skeyS, T);

    #pragma unroll
    for (int t = 0; t < 4; t++) skeyS[SK(4 * T + t)] = e[t];
    __syncthreads();

    if (T >= 64) return;
    const int lane = T;

    float* myScore = candScore + (size_t)n * CAND + c * K_MAX;
    float* myBox   = candBox   + ((size_t)n * CAND + c * K_MAX) * 4;

    int cnt = 0;
    bool done = false;

    for (int t = 0; t < 16 && !done; t++) {
        const int p = t * 64 + lane;
        const u64    key = skeyS[SK(p)];
        const int    b   = 1023 - (int)(unsigned)(key & 0xffffffffu);
        const float4 cb  = sbox[b];
        const bool valid = (key >> 32) != 0;
        const float carea = __fmul_rn(__fsub_rn(cb.z, cb.x), __fsub_rn(cb.w, cb.y));

        bool sup = false;
        for (int q = 0; q < cnt; q++) {
            float4 kb = keptB[q];
            float  ka = keptA[q];
            float iy1 = fmaxf(kb.x, cb.x), ix1 = fmaxf(kb.y, cb.y);
            float iy2 = fminf(kb.z, cb.z), ix2 = fminf(kb.w, cb.w);
            float ih  = fmaxf(__fsub_rn(iy2, iy1), 0.0f);
            float iw  = fmaxf(__fsub_rn(ix2, ix1), 0.0f);
            float inter = __fmul_rn(ih, iw);
            float den = fmaxf(__fsub_rn(__fadd_rn(ka, carea), inter), 1e-8f);
            sup = sup || ((double)inter > (double)den * CMP_IOU);
        }

        const u64 vmask = __ballot(valid);
        u64 alive = vmask & __ballot(!sup);

        while (alive != 0) {
            const int j = __ffsll(alive) - 1;
            const float bx = __int_as_float(__builtin_amdgcn_readlane(__float_as_int(cb.x), j));
            const float by = __int_as_float(__builtin_amdgcn_readlane(__float_as_int(cb.y), j));
            const float bz = __int_as_float(__builtin_amdgcn_readlane(__float_as_int(cb.z), j));
            const float bw = __int_as_float(__builtin_amdgcn_readlane(__float_as_int(cb.w), j));
            const float ba = __int_as_float(__builtin_amdgcn_readlane(__float_as_int(carea), j));

            if (lane == j) {
                myScore[cnt] = __uint_as_float((unsigned)(key >> 32));
                ((float4*)myBox)[cnt] = cb;
                keptB[cnt] = cb;
                keptA[cnt] = carea;
            }
            cnt++;
            if (cnt >= K_MAX) { done = true; break; }

            alive &= ~(1ull << j);
            if (alive != 0) {
                float iy1 = fmaxf(bx, cb.x), ix1 = fmaxf(by, cb.y);
                float iy2 = fminf(bz, cb.z), ix2 = fminf(bw, cb.w);
                float ih  = fmaxf(__fsub_rn(iy2, iy1), 0.0f);
                float iw  = fmaxf(__fsub_rn(ix2, ix1), 0.0f);
                float inter = __fmul_rn(ih, iw);
                float den = fmaxf(__fsub_rn(__fadd_rn(ba, carea), inter), 1e-8f);
                bool s2 = (double)inter > (double)den * CMP_IOU;
                alive &= ~__ballot(s2);
            }
        }

        if (vmask != ~0ull) done = true;
    }
    for (int q = cnt + lane; q < K_MAX; q += 64) myScore[q] = -1.0f;
}

// ---------------------------------------------------------------------------
// Top-K stage 1 (R9): 8 chunks/image x 8 images = 64 blocks.  Each chunk
// sorts its 10 classes x 100 candidates (1000 keys, zero-padded to 1024 —
// pads sort below any real key since the position field >= 192) with the
// verified bitonic, and writes its top 128 keys.  Global top-100 is a subset
// of the per-chunk top-100s.  Same u64 key order as the verified radix
// kernel => identical selection/tie-breaks.
// ---------------------------------------------------------------------------
__global__ __launch_bounds__(256) void topk_part_kernel(
    const float* __restrict__ candScore,  // [N][CAND]
    u64* __restrict__ selK)               // [N][8][128]
{
    __shared__ u64 skeyS[1024 + 32];

    const int n  = blockIdx.x >> 3;
    const int ch = blockIdx.x & 7;
    const int T  = threadIdx.x;

    u64 e[4];
    #pragma unroll
    for (int t = 0; t < 4; t++) {
        const int p = 4 * T + t;
        if (p < 1000) {
            const int i = ch * 1000 + p;           // per-image CAND index
            float s = candScore[(size_t)n * CAND + i];
            unsigned U = (s > 0.0f) ? __float_as_uint(s) : 0u;
            e[t] = (((u64)U) << 13) | (unsigned)(8191 - i);
        } else {
            e[t] = 0ull;
        }
    }

    bitonic1024(e, skeyS, T);

    if (T < 32) {
        #pragma unroll
        for (int t = 0; t < 4; t++)
            selK[((size_t)n * 8 + ch) * 128 + 4 * T + t] = e[t];
    }
}

// ---------------------------------------------------------------------------
// Top-K stage 2 (R9): one block per image.  Sort the 8 x 100 surviving keys
// (800, zero-padded to 1024) with the same bitonic; positions 0..99 are the
// global top-100 in rank order.  Gather boxes, write outputs (same layout &
// semantics as the verified radix kernel).
// ---------------------------------------------------------------------------
__global__ __launch_bounds__(256) void topk_merge_kernel(
    const u64* __restrict__ selK,        // [N][8][128]
    const float* __restrict__ candBox,   // [N][CAND][4]
    float* __restrict__ out)
{
    __shared__ u64 skeyS[1024 + 32];
    __shared__ int cntv;

    const int n = blockIdx.x;
    const int T = threadIdx.x;
    if (T == 0) cntv = 0;

    u64 e[4];
    #pragma unroll
    for (int t = 0; t < 4; t++) {
        const int p = 4 * T + t;
        if (p < 800) {
            const int ch = p / 100, j = p - ch * 100;   // first 100 of each
            e[t] = selK[((size_t)n * 8 + ch) * 128 + j];
        } else {
            e[t] = 0ull;
        }
    }

    bitonic1024(e, skeyS, T);   // contains barriers; cntv=0 ordered before use

    #pragma unroll
    for (int t = 0; t < 4; t++) {
        const int r = 4 * T + t;            // rank
        if (r < K_MAX) {
            const u64 key = e[t];
            const int q = 8191 - (int)(unsigned)(key & 0x1FFFu);
            const unsigned u = (unsigned)(key >> 13);
            const bool valid = (u != 0);
            float4 bx = make_float4(0.f, 0.f, 0.f, 0.f);
            if (valid) bx = ((const float4*)candBox)[(size_t)n * CAND + q];

            ((float4*)out)[n * K_MAX + r] = bx;
            out[N_IMG * K_MAX * 4 + n * K_MAX + r] = valid ? __uint_as_float(u) : 0.0f;
            out[N_IMG * K_MAX * 5 + n * K_MAX + r] = valid ? (float)(q / K_MAX) : 0.0f;
            if (valid) atomicAdd(&cntv, 1);
        }
    }
    __syncthreads();
    if (T == 0) out[N_IMG * K_MAX * 6 + n] = (float)cntv;
}

extern "C" void kernel_launch(void* const* d_in, const int* in_sizes, int n_in,
                              void* d_out, int out_size, void* d_ws, size_t ws_size,
                              hipStream_t stream) {
    const float* rois   = (const float*)d_in[0];   // [8][1000][4]
    const float* conf   = (const float*)d_in[1];   // [8][1000][81]
    const float* deltas = (const float*)d_in[2];   // [8][1000][320]
    float* out = (float*)d_out;                    // 36808 floats
    float* ws  = (float*)d_ws;

    float* candScore = ws;                                      // 64000 f
    float* candBox   = candScore + (size_t)N_IMG * CAND;        // 256000 f
    float* scoreT    = candBox + (size_t)N_IMG * CAND * 4;      // 655360 f
    float* boxT      = scoreT + (size_t)N_IMG * N_CLS * BPAD;   // 2621440 f
    u64*   skeyW     = (u64*)(boxT + (size_t)N_IMG * N_CLS * BPAD * 4);
    u64*   selW      = skeyW + (size_t)N_IMG * N_CLS * BPAD;    // 8192 u64
    const size_t needed = ((size_t)N_IMG * CAND * 5
                         + (size_t)N_IMG * N_CLS * BPAD * 5) * sizeof(float)
                        + ((size_t)N_IMG * N_CLS * BPAD + N_IMG * 8 * 128) * sizeof(u64);

    if (ws_size >= needed) {
        decode_kernel<<<N_IMG * NTILE, 256, 0, stream>>>(
            rois, conf, deltas, scoreT, boxT, out + 4808);
        sort_kernel<<<N_IMG * N_CLS, 256, 0, stream>>>(scoreT, skeyW);
        scan_kernel<<<N_IMG * N_CLS, 64, 0, stream>>>(
            skeyW, boxT, candScore, candBox);
        topk_part_kernel<<<N_IMG * 8, 256, 0, stream>>>(candScore, selW);
        topk_merge_kernel<<<N_IMG, 256, 0, stream>>>(selW, candBox, out);
    } else {
        u64* selF = (u64*)(candBox + (size_t)N_IMG * CAND * 4);
        nms_fused_kernel<<<N_IMG * N_CLS, 256, 0, stream>>>(
            rois, conf, deltas, candScore, candBox);
        topk_part_kernel<<<N_IMG * 8, 256, 0, stream>>>(candScore, selF);
        topk_merge_kernel<<<N_IMG, 256, 0, stream>>>(selF, candBox, out);
        hipMemcpyAsync(out + 4808, rois,
                       (size_t)N_IMG * B_BOX * 4 * sizeof(float),
                       hipMemcpyDeviceToDevice, stream);
    }
}

// Round 10
// 182.405 us; speedup vs baseline: 1.2233x; 1.0199x over previous
//
#include <hip/hip_runtime.h>
#include <cstddef>

#define N_IMG 8
#define B_BOX 1000
#define N_CLS 80
#define C1    81
#define K_MAX 100
#define CAND  (N_CLS * K_MAX)   // 8000
#define BPAD  1024              // padded boxes per class row

typedef unsigned long long u64;

// Exact threshold for fl32(a/b) > 0.5 under RNE:  a/b > 0.5 + 2^-25.
// (double)a > (double)b * CMP is exact: 24-bit x 25-bit significands <= 49 bits.
#define CMP_IOU (0.5 + 0x1p-25)

// Skewed index for the u64 sorted-key array: the bitonic j>=256 stages access
// stride-4 u64 (byte stride 32 = bank stride 8) -> 16-way conflict unskewed.
#define SK(p) ((p) + ((p) >> 5))

__device__ __forceinline__ u64 shfl_xor_u64(u64 x, int m) {
    unsigned lo = (unsigned)__shfl_xor((int)(unsigned)(x & 0xffffffffu), m);
    unsigned hi = (unsigned)__shfl_xor((int)(unsigned)(x >> 32), m);
    return ((u64)hi << 32) | lo;
}

// The verified 1024-key descending bitonic (R3/R7/R9): keys in e[4], p=4T+t.
// Independent per-t shuffles pipeline; only the j>=256 stages touch LDS.
__device__ __forceinline__ void bitonic1024(u64 e[4], u64* skeyS, int T) {
    #pragma unroll 1
    for (int k = 2; k <= 1024; k <<= 1) {
        #pragma unroll 1
        for (int j = (k >> 1); j >= 1; j >>= 1) {
            if (j >= 256) {
                #pragma unroll
                for (int t = 0; t < 4; t++) skeyS[SK(4 * T + t)] = e[t];
                __syncthreads();
                #pragma unroll
                for (int t = 0; t < 4; t++) {
                    int p = 4 * T + t;
                    u64 o = skeyS[SK(p ^ j)];
                    bool keepMin = (((p & j) == 0) == ((p & k) != 0));
                    u64 mn = (e[t] < o) ? e[t] : o;
                    u64 mx = (e[t] < o) ? o : e[t];
                    e[t] = keepMin ? mn : mx;
                }
                __syncthreads();
            } else if (j >= 4) {
                int jl = j >> 2;                        // lane distance
                bool lower = ((T & jl) == 0);           // == ((p&j)==0)
                bool up    = (((4 * T) & k) != 0);      // k>=8: t bits moot
                bool keepMin = (lower == up);
                #pragma unroll
                for (int t = 0; t < 4; t++) {
                    u64 o = shfl_xor_u64(e[t], jl);
                    u64 mn = (e[t] < o) ? e[t] : o;
                    u64 mx = (e[t] < o) ? o : e[t];
                    e[t] = keepMin ? mn : mx;
                }
            } else if (j == 2) {
                #pragma unroll
                for (int t = 0; t < 2; t++) {           // pairs (0,2),(1,3)
                    int p = 4 * T + t;
                    bool up = ((p & k) != 0);
                    u64 a = e[t], b = e[t + 2];
                    bool sw = up ? (a > b) : (a < b);
                    e[t]     = sw ? b : a;
                    e[t + 2] = sw ? a : b;
                }
            } else {                                    // j == 1: (0,1),(2,3)
                #pragma unroll
                for (int t = 0; t < 4; t += 2) {
                    int p = 4 * T + t;
                    bool up = ((p & k) != 0);
                    u64 a = e[t], b = e[t + 1];
                    bool sw = up ? (a > b) : (a < b);
                    e[t]     = sw ? b : a;
                    e[t + 1] = sw ? a : b;
                }
            }
        }
    }
}

__device__ __forceinline__ float4 decode_box(float4 rr, float4 dd) {
    // identical FP sequence to the verified kernels (contraction blocked)
    float w0 = __fadd_rn(__fsub_rn(rr.w, rr.y), 1.0f);
    float h0 = __fadd_rn(__fsub_rn(rr.z, rr.x), 1.0f);
    float x0 = __fadd_rn(rr.y, __fmul_rn(w0, 0.5f));
    float y0 = __fadd_rn(rr.x, __fmul_rn(h0, 0.5f));
    float tx = __fdiv_rn(dd.x, 10.0f);
    float ty = __fdiv_rn(dd.y, 10.0f);
    float tw = __fdiv_rn(dd.z, 5.0f);
    float th = __fdiv_rn(dd.w, 5.0f);
    float cx = __fadd_rn(__fmul_rn(tx, w0), x0);
    float cy = __fadd_rn(__fmul_rn(ty, h0), y0);
    float ww = __fmul_rn(expf(tw), w0);
    float hh = __fmul_rn(expf(th), h0);
    float xx1 = fminf(fmaxf(__fsub_rn(cx, __fmul_rn(0.5f, ww)), 0.0f), 799.0f);
    float yy1 = fminf(fmaxf(__fsub_rn(cy, __fmul_rn(0.5f, hh)), 0.0f), 799.0f);
    float xx2 = fminf(fmaxf(__fadd_rn(cx, __fmul_rn(0.5f, ww)), 0.0f), 799.0f);
    float yy2 = fminf(fmaxf(__fadd_rn(cy, __fmul_rn(0.5f, hh)), 0.0f), 799.0f);
    return make_float4(yy1, xx1, yy2, xx2);
}

// ---------------------------------------------------------------------------
// Decode/transpose (verified, unchanged).
// ---------------------------------------------------------------------------
#define TILE  16
#define NTILE 63
__global__ __launch_bounds__(256) void decode_kernel(
    const float* __restrict__ rois,
    const float* __restrict__ conf,
    const float* __restrict__ deltas,
    float* __restrict__ scoreT,          // [N][80][1024]
    float* __restrict__ boxT,            // [N][80][1024][4]
    float* __restrict__ outRois)
{
    __shared__ float4 lrois[TILE];
    __shared__ float4 lbox[16][TILE + 1];
    __shared__ float  lsc[16][TILE + 1];

    const int tid  = threadIdx.x;
    const int n    = blockIdx.x / NTILE;
    const int tile = blockIdx.x % NTILE;
    const int b0   = tile * TILE;
    const float4 INERT = make_float4(1.0e9f, 1.0e9f, -1.0e9f, -1.0e9f);

    {
        int gidx = blockIdx.x * 256 + tid;
        if (gidx < N_IMG * B_BOX * 4) outRois[gidx] = rois[gidx];
    }

    if (tid < TILE) {
        int b = b0 + tid;
        lrois[tid] = (b < B_BOX) ? ((const float4*)rois)[n * B_BOX + b]
                                 : make_float4(0.f, 0.f, 0.f, 0.f);
    }
    __syncthreads();

    #pragma unroll
    for (int c0 = 0; c0 < N_CLS; c0 += 16) {
        {
            int bl = tid >> 4, ci = tid & 15;
            int b = b0 + bl, c = c0 + ci;
            float4 bx; float sc;
            if (b < B_BOX) {
                float4 dd = ((const float4*)deltas)[(n * B_BOX + b) * N_CLS + c];
                sc = conf[((size_t)(n * B_BOX + b)) * C1 + c];
                bx = decode_box(lrois[bl], dd);
            } else { bx = INERT; sc = 0.0f; }
            lbox[ci][bl] = bx; lsc[ci][bl] = sc;
        }
        __syncthreads();
        {
            int cc = tid >> 4, bl = tid & 15;
            size_t row = ((size_t)n * N_CLS + c0 + cc) * BPAD + b0 + bl;
            ((float4*)boxT)[row] = lbox[cc][bl];
            scoreT[row] = lsc[cc][bl];
        }
        __syncthreads();
    }

    if (tile == 0) {
        for (int i = tid; i < N_CLS * 16; i += 256) {
            int c = i >> 4, b = 1008 + (i & 15);
            size_t row = ((size_t)n * N_CLS + c) * BPAD + b;
            ((float4*)boxT)[row] = INERT;
            scoreT[row] = 0.0f;
        }
    }
}

// ---------------------------------------------------------------------------
// Fused NMS (R3-verbatim — the directly-measured best sort+scan structure,
// 47-49 us): 256 threads per (image, class); bitonic sort with skewed key
// array; wave-0 batch-parallel greedy scan, sbox read through the key.
// ---------------------------------------------------------------------------
template <bool PRE>
__global__ __launch_bounds__(256) void nms_kernel(
    const float* __restrict__ rois,
    const float* __restrict__ conf,
    const float* __restrict__ deltas,
    const float* __restrict__ scoreT,
    const float* __restrict__ boxT,
    float* __restrict__ candScore,       // [N][CAND]
    float* __restrict__ candBox)         // [N][CAND][4]
{
    __shared__ float4 sbox[1024];
    __shared__ u64    skeyS[1024 + 32];  // skewed (SK)
    __shared__ float4 keptB[K_MAX];
    __shared__ float  keptA[K_MAX];

    const int n = blockIdx.x / N_CLS;
    const int c = blockIdx.x % N_CLS;
    const int T = threadIdx.x;
    const float4 INERT = make_float4(1.0e9f, 1.0e9f, -1.0e9f, -1.0e9f);

    u64 e[4];

    if (PRE) {
        const size_t row = ((size_t)n * N_CLS + c) * BPAD;
        #pragma unroll
        for (int t = 0; t < 4; t++) {
            const int p = 4 * T + t;               // 64B/lane contiguous
            float4 q = ((const float4*)boxT)[row + p];
            float sc = scoreT[row + p];
            sbox[p] = q;
            unsigned sb = (sc > 0.05f) ? __float_as_uint(sc) : 0u;
            e[t] = ((u64)sb << 32) | (unsigned)(1023 - p);
        }
    } else {
        #pragma unroll
        for (int t = 0; t < 4; t++) {
            const int p = 4 * T + t;
            if (p < B_BOX) {
                float4 rr = ((const float4*)rois)[n * B_BOX + p];
                float4 dd = ((const float4*)deltas)[(size_t)(n * B_BOX + p) * N_CLS + c];
                float score = conf[((size_t)(n * B_BOX + p)) * C1 + c];
                float4 q = decode_box(rr, dd);
                sbox[p] = q;
                unsigned sb = (score > 0.05f) ? __float_as_uint(score) : 0u;
                e[t] = ((u64)sb << 32) | (unsigned)(1023 - p);
            } else {
                sbox[p] = INERT;
                e[t] = (u64)(unsigned)(1023 - p);
            }
        }
    }

    bitonic1024(e, skeyS, T);

    #pragma unroll
    for (int t = 0; t < 4; t++) skeyS[SK(4 * T + t)] = e[t];
    __syncthreads();

    if (T >= 64) return;          // waves 1-3 done; scan has no barriers
    const int lane = T;

    float* myScore = candScore + (size_t)n * CAND + c * K_MAX;
    float* myBox   = candBox   + ((size_t)n * CAND + c * K_MAX) * 4;

    int cnt = 0;
    bool done = false;

    for (int t = 0; t < 16 && !done; t++) {
        const int p = t * 64 + lane;
        const u64    key = skeyS[SK(p)];
        const int    b   = 1023 - (int)(unsigned)(key & 0xffffffffu);
        const float4 cb  = sbox[b];
        const bool valid = (key >> 32) != 0;
        const float carea = __fmul_rn(__fsub_rn(cb.z, cb.x), __fsub_rn(cb.w, cb.y));

        bool sup = false;
        for (int q = 0; q < cnt; q++) {
            float4 kb = keptB[q];
            float  ka = keptA[q];
            float iy1 = fmaxf(kb.x, cb.x), ix1 = fmaxf(kb.y, cb.y);
            float iy2 = fminf(kb.z, cb.z), ix2 = fminf(kb.w, cb.w);
            float ih  = fmaxf(__fsub_rn(iy2, iy1), 0.0f);
            float iw  = fmaxf(__fsub_rn(ix2, ix1), 0.0f);
            float inter = __fmul_rn(ih, iw);
            float den = fmaxf(__fsub_rn(__fadd_rn(ka, carea), inter), 1e-8f);
            sup = sup || ((double)inter > (double)den * CMP_IOU);
        }

        const u64 vmask = __ballot(valid);
        u64 alive = vmask & __ballot(!sup);

        while (alive != 0) {
            const int j = __ffsll(alive) - 1;
            const float bx = __int_as_float(__builtin_amdgcn_readlane(__float_as_int(cb.x), j));
            const float by = __int_as_float(__builtin_amdgcn_readlane(__float_as_int(cb.y), j));
            const float bz = __int_as_float(__builtin_amdgcn_readlane(__float_as_int(cb.z), j));
            const float bw = __int_as_float(__builtin_amdgcn_readlane(__float_as_int(cb.w), j));
            const float ba = __int_as_float(__builtin_amdgcn_readlane(__float_as_int(carea), j));

            if (lane == j) {
                myScore[cnt] = __uint_as_float((unsigned)(key >> 32));
                ((float4*)myBox)[cnt] = cb;
                keptB[cnt] = cb;
                keptA[cnt] = carea;
            }
            cnt++;
            if (cnt >= K_MAX) { done = true; break; }

            alive &= ~(1ull << j);
            if (alive != 0) {
                float iy1 = fmaxf(bx, cb.x), ix1 = fmaxf(by, cb.y);
                float iy2 = fminf(bz, cb.z), ix2 = fminf(bw, cb.w);
                float ih  = fmaxf(__fsub_rn(iy2, iy1), 0.0f);
                float iw  = fmaxf(__fsub_rn(ix2, ix1), 0.0f);
                float inter = __fmul_rn(ih, iw);
                float den = fmaxf(__fsub_rn(__fadd_rn(ba, carea), inter), 1e-8f);
                bool s2 = (double)inter > (double)den * CMP_IOU;
                alive &= ~__ballot(s2);
            }
        }

        if (vmask != ~0ull) done = true;
    }
    for (int q = cnt + lane; q < K_MAX; q += 64) myScore[q] = -1.0f;
}

// ---------------------------------------------------------------------------
// Top-K stage 1 (R9-verified): 8 chunks/image x 8 images = 64 blocks.  Each
// chunk sorts its 10x100 candidates (zero-padded to 1024) with the verified
// bitonic and writes its top 128 keys.  Same u64 key order as the original
// radix kernel => identical selection/tie-breaks.
// ---------------------------------------------------------------------------
__global__ __launch_bounds__(256) void topk_part_kernel(
    const float* __restrict__ candScore,  // [N][CAND]
    u64* __restrict__ selK)               // [N][8][128]
{
    __shared__ u64 skeyS[1024 + 32];

    const int n  = blockIdx.x >> 3;
    const int ch = blockIdx.x & 7;
    const int T  = threadIdx.x;

    u64 e[4];
    #pragma unroll
    for (int t = 0; t < 4; t++) {
        const int p = 4 * T + t;
        if (p < 1000) {
            const int i = ch * 1000 + p;           // per-image CAND index
            float s = candScore[(size_t)n * CAND + i];
            unsigned U = (s > 0.0f) ? __float_as_uint(s) : 0u;
            e[t] = (((u64)U) << 13) | (unsigned)(8191 - i);
        } else {
            e[t] = 0ull;
        }
    }

    bitonic1024(e, skeyS, T);

    if (T < 32) {
        #pragma unroll
        for (int t = 0; t < 4; t++)
            selK[((size_t)n * 8 + ch) * 128 + 4 * T + t] = e[t];
    }
}

// ---------------------------------------------------------------------------
// Top-K stage 2 (R9-verified): one block per image.  Sort the 8x100
// survivors (zero-padded to 1024); ranks 0..99 are the global top-100.
// ---------------------------------------------------------------------------
__global__ __launch_bounds__(256) void topk_merge_kernel(
    const u64* __restrict__ selK,        // [N][8][128]
    const float* __restrict__ candBox,   // [N][CAND][4]
    float* __restrict__ out)
{
    __shared__ u64 skeyS[1024 + 32];
    __shared__ int cntv;

    const int n = blockIdx.x;
    const int T = threadIdx.x;
    if (T == 0) cntv = 0;

    u64 e[4];
    #pragma unroll
    for (int t = 0; t < 4; t++) {
        const int p = 4 * T + t;
        if (p < 800) {
            const int ch = p / 100, j = p - ch * 100;   // first 100 of each
            e[t] = selK[((size_t)n * 8 + ch) * 128 + j];
        } else {
            e[t] = 0ull;
        }
    }

    bitonic1024(e, skeyS, T);   // contains barriers; cntv=0 ordered before use

    #pragma unroll
    for (int t = 0; t < 4; t++) {
        const int r = 4 * T + t;            // rank
        if (r < K_MAX) {
            const u64 key = e[t];
            const int q = 8191 - (int)(unsigned)(key & 0x1FFFu);
            const unsigned u = (unsigned)(key >> 13);
            const bool valid = (u != 0);
            float4 bx = make_float4(0.f, 0.f, 0.f, 0.f);
            if (valid) bx = ((const float4*)candBox)[(size_t)n * CAND + q];

            ((float4*)out)[n * K_MAX + r] = bx;
            out[N_IMG * K_MAX * 4 + n * K_MAX + r] = valid ? __uint_as_float(u) : 0.0f;
            out[N_IMG * K_MAX * 5 + n * K_MAX + r] = valid ? (float)(q / K_MAX) : 0.0f;
            if (valid) atomicAdd(&cntv, 1);
        }
    }
    __syncthreads();
    if (T == 0) out[N_IMG * K_MAX * 6 + n] = (float)cntv;
}

extern "C" void kernel_launch(void* const* d_in, const int* in_sizes, int n_in,
                              void* d_out, int out_size, void* d_ws, size_t ws_size,
                              hipStream_t stream) {
    const float* rois   = (const float*)d_in[0];   // [8][1000][4]
    const float* conf   = (const float*)d_in[1];   // [8][1000][81]
    const float* deltas = (const float*)d_in[2];   // [8][1000][320]
    float* out = (float*)d_out;                    // 36808 floats
    float* ws  = (float*)d_ws;

    float* candScore = ws;                                      // 64000 f
    float* candBox   = candScore + (size_t)N_IMG * CAND;        // 256000 f
    float* scoreT    = candBox + (size_t)N_IMG * CAND * 4;      // 655360 f
    float* boxT      = scoreT + (size_t)N_IMG * N_CLS * BPAD;   // 2621440 f
    u64*   selW      = (u64*)(boxT + (size_t)N_IMG * N_CLS * BPAD * 4);
    const size_t needed = ((size_t)N_IMG * CAND * 5
                         + (size_t)N_IMG * N_CLS * BPAD * 5) * sizeof(float)
                        + (size_t)N_IMG * 8 * 128 * sizeof(u64);

    if (ws_size >= needed) {
        decode_kernel<<<N_IMG * NTILE, 256, 0, stream>>>(
            rois, conf, deltas, scoreT, boxT, out + 4808);
        nms_kernel<true><<<N_IMG * N_CLS, 256, 0, stream>>>(
            rois, conf, deltas, scoreT, boxT, candScore, candBox);
        topk_part_kernel<<<N_IMG * 8, 256, 0, stream>>>(candScore, selW);
        topk_merge_kernel<<<N_IMG, 256, 0, stream>>>(selW, candBox, out);
    } else {
        u64* selF = (u64*)(candBox + (size_t)N_IMG * CAND * 4);
        nms_kernel<false><<<N_IMG * N_CLS, 256, 0, stream>>>(
            rois, conf, deltas, nullptr, nullptr, candScore, candBox);
        topk_part_kernel<<<N_IMG * 8, 256, 0, stream>>>(candScore, selF);
        topk_merge_kernel<<<N_IMG, 256, 0, stream>>>(selF, candBox, out);
        hipMemcpyAsync(out + 4808, rois,
                       (size_t)N_IMG * B_BOX * 4 * sizeof(float),
                       hipMemcpyDeviceToDevice, stream);
    }
}